// Round 1
// baseline (631.815 us; speedup 1.0000x reference)
//
#include <hip/hip_runtime.h>
#include <math.h>

#define TOK  1024
#define HID  1024
#define NEXP 16

#define BM 64
#define BN 64
#define BK 16

// ---------------- zero the expert counters (ws is poisoned every launch) ----
__global__ void k_zero(int* __restrict__ counts) {
    if (threadIdx.x < 32) counts[threadIdx.x] = 0;
}

// ---------------- router: 1 wave per token --------------------------------
__global__ __launch_bounds__(64)
void k_router(const float* __restrict__ x, const int* __restrict__ tt,
              const float* __restrict__ rw_t, const float* __restrict__ b_t,
              const float* __restrict__ rw_v, const float* __restrict__ b_v,
              float* __restrict__ out_logits,
              int* __restrict__ counts, int* __restrict__ lists,
              float* __restrict__ wlist)
{
    const int t = blockIdx.x;
    const int lane = threadIdx.x;
    const bool vis = (tt[t] != 0);
    const float* rw   = vis ? rw_v : rw_t;
    const float* bias = vis ? b_v  : b_t;
    const float* xr = x + (size_t)t * HID;

    float acc[NEXP];
#pragma unroll
    for (int e = 0; e < NEXP; ++e) acc[e] = 0.f;
    for (int j = 0; j < HID; j += 64) {
        const float xv = xr[j + lane];
#pragma unroll
        for (int e = 0; e < NEXP; ++e)
            acc[e] = fmaf(xv, rw[(size_t)e * HID + j + lane], acc[e]);
    }
#pragma unroll
    for (int e = 0; e < NEXP; ++e) {
        float v = acc[e];
#pragma unroll
        for (int off = 32; off; off >>= 1) v += __shfl_xor(v, off);
        acc[e] = v;
    }
    if (lane < NEXP) out_logits[(size_t)t * NEXP + lane] = acc[lane];

    if (lane == 0) {
        float mx = acc[0];
#pragma unroll
        for (int e = 1; e < NEXP; ++e) mx = fmaxf(mx, acc[e]);
        float p[NEXP], s = 0.f;
#pragma unroll
        for (int e = 0; e < NEXP; ++e) { p[e] = expf(acc[e] - mx); s += p[e]; }
        const float inv = 1.f / s;
#pragma unroll
        for (int e = 0; e < NEXP; ++e) p[e] *= inv;

        // top-2 on bias-corrected probs; strict > keeps lowest index on ties
        int s1 = 0; float v1 = p[0] + bias[0];
#pragma unroll
        for (int e = 1; e < NEXP; ++e) {
            float c = p[e] + bias[e];
            if (c > v1) { v1 = c; s1 = e; }
        }
        int s2 = -1; float v2 = -1e30f;
#pragma unroll
        for (int e = 0; e < NEXP; ++e) {
            if (e == s1) continue;
            float c = p[e] + bias[e];
            if (c > v2) { v2 = c; s2 = e; }
        }
        float w1 = p[s1], w2 = p[s2];
        float sw = fmaxf(w1 + w2, 1e-12f);
        w1 /= sw; w2 /= sw;

        const int base = vis ? NEXP : 0;
        int pos1 = atomicAdd(&counts[base + s1], 1);
        lists[(base + s1) * TOK + pos1] = t * 2 + 0;
        wlist[(base + s1) * TOK + pos1] = w1;
        int pos2 = atomicAdd(&counts[base + s2], 1);
        lists[(base + s2) * TOK + pos2] = t * 2 + 1;
        wlist[(base + s2) * TOK + pos2] = w2;
    }
}

// ---------------- shared expert: gate & up GEMM + silu*mul -> Hs ----------
__global__ __launch_bounds__(256)
void k_shared_gu(const float* __restrict__ X, const float* __restrict__ Wg,
                 const float* __restrict__ Wu, float* __restrict__ Hs)
{
    __shared__ float As[BK][BM + 4];
    __shared__ float Bg[BK][BN + 4];
    __shared__ float Bu[BK][BN + 4];
    const int m0 = blockIdx.y * BM, n0 = blockIdx.x * BN;
    const int tid = threadIdx.x;
    const int tx = tid & 15, ty = tid >> 4;
    const int lr = tid >> 2, lk = (tid & 3) * 4;
    const int bk = tid >> 4, bc = (tid & 15) * 4;
    float ag[4][4] = {{0.f}}, au[4][4] = {{0.f}};

    for (int k0 = 0; k0 < HID; k0 += BK) {
        float4 a4 = *(const float4*)(X + (size_t)(m0 + lr) * HID + k0 + lk);
        As[lk + 0][lr] = a4.x; As[lk + 1][lr] = a4.y;
        As[lk + 2][lr] = a4.z; As[lk + 3][lr] = a4.w;
        *(float4*)&Bg[bk][bc] = *(const float4*)(Wg + (size_t)(k0 + bk) * 1024 + n0 + bc);
        *(float4*)&Bu[bk][bc] = *(const float4*)(Wu + (size_t)(k0 + bk) * 1024 + n0 + bc);
        __syncthreads();
#pragma unroll
        for (int k = 0; k < BK; ++k) {
            float a[4], bg[4], bu[4];
            *(float4*)a  = *(const float4*)&As[k][ty * 4];
            *(float4*)bg = *(const float4*)&Bg[k][tx * 4];
            *(float4*)bu = *(const float4*)&Bu[k][tx * 4];
#pragma unroll
            for (int i = 0; i < 4; ++i)
#pragma unroll
                for (int j = 0; j < 4; ++j) {
                    ag[i][j] = fmaf(a[i], bg[j], ag[i][j]);
                    au[i][j] = fmaf(a[i], bu[j], au[i][j]);
                }
        }
        __syncthreads();
    }
#pragma unroll
    for (int i = 0; i < 4; ++i)
#pragma unroll
        for (int j = 0; j < 4; ++j) {
            float g = ag[i][j], u = au[i][j];
            float h = g / (1.f + expf(-g)) * u;
            Hs[(size_t)(m0 + ty * 4 + i) * 1024 + n0 + tx * 4 + j] = h;
        }
}

// ---------------- shared expert: down GEMM, plain store (initializes out) --
__global__ __launch_bounds__(256)
void k_shared_down(const float* __restrict__ Hs, const float* __restrict__ Wd,
                   float* __restrict__ out)
{
    __shared__ float As[BK][BM + 4];
    __shared__ float Bs[BK][BN + 4];
    const int m0 = blockIdx.y * BM, n0 = blockIdx.x * BN;
    const int tid = threadIdx.x;
    const int tx = tid & 15, ty = tid >> 4;
    const int lr = tid >> 2, lk = (tid & 3) * 4;
    const int bk = tid >> 4, bc = (tid & 15) * 4;
    float acc[4][4] = {{0.f}};

    for (int k0 = 0; k0 < 1024; k0 += BK) {
        float4 a4 = *(const float4*)(Hs + (size_t)(m0 + lr) * 1024 + k0 + lk);
        As[lk + 0][lr] = a4.x; As[lk + 1][lr] = a4.y;
        As[lk + 2][lr] = a4.z; As[lk + 3][lr] = a4.w;
        *(float4*)&Bs[bk][bc] = *(const float4*)(Wd + (size_t)(k0 + bk) * HID + n0 + bc);
        __syncthreads();
#pragma unroll
        for (int k = 0; k < BK; ++k) {
            float a[4], b[4];
            *(float4*)a = *(const float4*)&As[k][ty * 4];
            *(float4*)b = *(const float4*)&Bs[k][tx * 4];
#pragma unroll
            for (int i = 0; i < 4; ++i)
#pragma unroll
                for (int j = 0; j < 4; ++j)
                    acc[i][j] = fmaf(a[i], b[j], acc[i][j]);
        }
        __syncthreads();
    }
#pragma unroll
    for (int i = 0; i < 4; ++i)
#pragma unroll
        for (int j = 0; j < 4; ++j)
            out[(size_t)(m0 + ty * 4 + i) * HID + n0 + tx * 4 + j] = acc[i][j];
}

// ---------------- routed experts: X_gathered @ gate_up_e -> gu_buf ---------
__global__ __launch_bounds__(256)
void k_routed_gu(const float* __restrict__ X,
                 const float* __restrict__ gut, const float* __restrict__ guv,
                 const int* __restrict__ counts, const int* __restrict__ lists,
                 float* __restrict__ gu_buf)
{
    const int es = blockIdx.z;
    const int mod = es >> 4, e = es & 15;
    const int M = counts[es];
    if ((int)blockIdx.y * BM >= M) return;
    const int N2 = mod ? 512 : 1024;
    const int n0 = blockIdx.x * BN;
    if (n0 >= N2) return;
    const float* Bw = mod ? (guv + (size_t)e * HID * 512)
                          : (gut + (size_t)e * HID * 1024);

    __shared__ int s_aid[BM];
    __shared__ float As[BK][BM + 4];
    __shared__ float Bs[BK][BN + 4];
    const int tid = threadIdx.x;
    if (tid < BM) {
        int r = blockIdx.y * BM + tid;
        s_aid[tid] = (r < M) ? lists[es * TOK + r] : -1;
    }
    __syncthreads();
    const int tx = tid & 15, ty = tid >> 4;
    const int lr = tid >> 2, lk = (tid & 3) * 4;
    const int bk = tid >> 4, bc = (tid & 15) * 4;
    const int arow = (s_aid[lr] >= 0) ? (s_aid[lr] >> 1) : 0;
    float acc[4][4] = {{0.f}};

    for (int k0 = 0; k0 < HID; k0 += BK) {
        float4 a4 = *(const float4*)(X + (size_t)arow * HID + k0 + lk);
        As[lk + 0][lr] = a4.x; As[lk + 1][lr] = a4.y;
        As[lk + 2][lr] = a4.z; As[lk + 3][lr] = a4.w;
        *(float4*)&Bs[bk][bc] = *(const float4*)(Bw + (size_t)(k0 + bk) * N2 + n0 + bc);
        __syncthreads();
#pragma unroll
        for (int k = 0; k < BK; ++k) {
            float a[4], b[4];
            *(float4*)a = *(const float4*)&As[k][ty * 4];
            *(float4*)b = *(const float4*)&Bs[k][tx * 4];
#pragma unroll
            for (int i = 0; i < 4; ++i)
#pragma unroll
                for (int j = 0; j < 4; ++j)
                    acc[i][j] = fmaf(a[i], b[j], acc[i][j]);
        }
        __syncthreads();
    }
#pragma unroll
    for (int i = 0; i < 4; ++i) {
        int r = ty * 4 + i;
        int aid = s_aid[r];
        if (aid < 0) continue;
#pragma unroll
        for (int j = 0; j < 4; ++j)
            gu_buf[(size_t)aid * 1024 + n0 + tx * 4 + j] = acc[i][j];
    }
}

// ---------------- routed experts: silu(g)*u @ down_e -> atomicAdd out ------
__global__ __launch_bounds__(256)
void k_routed_down(const float* __restrict__ gu_buf,
                   const float* __restrict__ dnt, const float* __restrict__ dnv,
                   const int* __restrict__ counts, const int* __restrict__ lists,
                   const float* __restrict__ wlist,
                   float* __restrict__ out)
{
    const int es = blockIdx.z;
    const int mod = es >> 4, e = es & 15;
    const int M = counts[es];
    if ((int)blockIdx.y * BM >= M) return;
    const int I = mod ? 256 : 512;
    const int n0 = blockIdx.x * BN;
    const float* Bw = mod ? (dnv + (size_t)e * 256 * 1024)
                          : (dnt + (size_t)e * 512 * 1024);

    __shared__ int s_aid[BM];
    __shared__ float s_w[BM];
    __shared__ float As[BK][BM + 4];
    __shared__ float Bs[BK][BN + 4];
    const int tid = threadIdx.x;
    if (tid < BM) {
        int r = blockIdx.y * BM + tid;
        if (r < M) { s_aid[tid] = lists[es * TOK + r]; s_w[tid] = wlist[es * TOK + r]; }
        else       { s_aid[tid] = -1; s_w[tid] = 0.f; }
    }
    __syncthreads();
    const int tx = tid & 15, ty = tid >> 4;
    const int lr = tid >> 2, lk = (tid & 3) * 4;
    const int bk = tid >> 4, bc = (tid & 15) * 4;
    const size_t abase = (size_t)((s_aid[lr] >= 0) ? s_aid[lr] : 0) * 1024;
    float acc[4][4] = {{0.f}};

    for (int k0 = 0; k0 < I; k0 += BK) {
        float4 g4 = *(const float4*)(gu_buf + abase + k0 + lk);
        float4 u4 = *(const float4*)(gu_buf + abase + I + k0 + lk);
        As[lk + 0][lr] = g4.x / (1.f + expf(-g4.x)) * u4.x;
        As[lk + 1][lr] = g4.y / (1.f + expf(-g4.y)) * u4.y;
        As[lk + 2][lr] = g4.z / (1.f + expf(-g4.z)) * u4.z;
        As[lk + 3][lr] = g4.w / (1.f + expf(-g4.w)) * u4.w;
        *(float4*)&Bs[bk][bc] = *(const float4*)(Bw + (size_t)(k0 + bk) * HID + n0 + bc);
        __syncthreads();
#pragma unroll
        for (int k = 0; k < BK; ++k) {
            float a[4], b[4];
            *(float4*)a = *(const float4*)&As[k][ty * 4];
            *(float4*)b = *(const float4*)&Bs[k][tx * 4];
#pragma unroll
            for (int i = 0; i < 4; ++i)
#pragma unroll
                for (int j = 0; j < 4; ++j)
                    acc[i][j] = fmaf(a[i], b[j], acc[i][j]);
        }
        __syncthreads();
    }
#pragma unroll
    for (int i = 0; i < 4; ++i) {
        int r = ty * 4 + i;
        int aid = s_aid[r];
        if (aid < 0) continue;
        int tok = aid >> 1;
        float w = s_w[r];
#pragma unroll
        for (int j = 0; j < 4; ++j)
            atomicAdd(&out[(size_t)tok * HID + n0 + tx * 4 + j], w * acc[i][j]);
    }
}

extern "C" void kernel_launch(void* const* d_in, const int* in_sizes, int n_in,
                              void* d_out, int out_size, void* d_ws, size_t ws_size,
                              hipStream_t stream)
{
    const float* x    = (const float*)d_in[0];
    const int*   tt   = (const int*)d_in[1];
    const float* rw_t = (const float*)d_in[2];
    const float* b_t  = (const float*)d_in[3];
    const float* gu_t = (const float*)d_in[4];
    const float* dn_t = (const float*)d_in[5];
    const float* rw_v = (const float*)d_in[6];
    const float* b_v  = (const float*)d_in[7];
    const float* gu_v = (const float*)d_in[8];
    const float* dn_v = (const float*)d_in[9];
    const float* sg   = (const float*)d_in[10];
    const float* su   = (const float*)d_in[11];
    const float* sd   = (const float*)d_in[12];
    float* out = (float*)d_out;
    float* out_logits = out + (size_t)TOK * HID;

    char* ws = (char*)d_ws;
    int*   counts = (int*)ws;                                  // 32 ints
    int*   lists  = (int*)(ws + 1024);                         // 32*1024 ints
    float* wlist  = (float*)(ws + 1024 + 32 * TOK * 4);        // 32*1024 floats
    float* big    = (float*)(ws + 1024 + 64 * TOK * 4);        // 8 MB region
    float* Hs     = big;        // [1024][1024], live B1->B2
    float* gu_buf = big;        // [2048][1024], live C1->C2 (aliased, disjoint lifetime)

    hipLaunchKernelGGL(k_zero, dim3(1), dim3(32), 0, stream, counts);
    hipLaunchKernelGGL(k_router, dim3(TOK), dim3(64), 0, stream,
                       x, tt, rw_t, b_t, rw_v, b_v, out_logits, counts, lists, wlist);
    hipLaunchKernelGGL(k_shared_gu, dim3(16, 16), dim3(256), 0, stream, x, sg, su, Hs);
    hipLaunchKernelGGL(k_shared_down, dim3(16, 16), dim3(256), 0, stream, Hs, sd, out);
    hipLaunchKernelGGL(k_routed_gu, dim3(16, 16, 32), dim3(256), 0, stream,
                       x, gu_t, gu_v, counts, lists, gu_buf);
    hipLaunchKernelGGL(k_routed_down, dim3(16, 16, 32), dim3(256), 0, stream,
                       gu_buf, dn_t, dn_v, counts, lists, wlist, out);
}

// Round 2
// 450.541 us; speedup vs baseline: 1.4023x; 1.4023x over previous
//
#include <hip/hip_runtime.h>
#include <math.h>

#define TOK  1024
#define HID  1024
#define NEXP 16

typedef __attribute__((ext_vector_type(8))) short bf16x8;
typedef __attribute__((ext_vector_type(4))) float f32x4;
typedef __attribute__((ext_vector_type(8))) unsigned short u16x8;

__device__ __forceinline__ short f2bf(float f) {           // round-half-up bf16
    union { float f; unsigned u; } v; v.f = f;
    unsigned r = v.u + 0x8000u;
    return (short)(r >> 16);
}
__device__ __forceinline__ float bf2f(unsigned short h) {
    union { unsigned u; float f; } v; v.u = ((unsigned)h) << 16;
    return v.f;
}
// pack hi16(f0) | hi16(f1)<<16 with round-half-up
__device__ __forceinline__ unsigned pack2(float f0, float f1) {
    union { float f; unsigned u; } a, b; a.f = f0; b.f = f1;
    return __builtin_amdgcn_perm(b.u + 0x8000u, a.u + 0x8000u, 0x07060302u);
}

// ---------------- init: zero counts + zero final-out region ----------------
__global__ void k_init(float* __restrict__ out, int* __restrict__ counts) {
    size_t i = (size_t)blockIdx.x * blockDim.x + threadIdx.x;   // 262144 float4
    ((float4*)out)[i] = make_float4(0.f, 0.f, 0.f, 0.f);
    if (blockIdx.x == 0 && threadIdx.x < 32) counts[threadIdx.x] = 0;
}

// ---------------- router: 1 wave per token (fp32 exact) --------------------
__global__ __launch_bounds__(64)
void k_router(const float* __restrict__ x, const int* __restrict__ tt,
              const float* __restrict__ rw_t, const float* __restrict__ b_t,
              const float* __restrict__ rw_v, const float* __restrict__ b_v,
              float* __restrict__ out_logits,
              int* __restrict__ counts, int* __restrict__ lists,
              float* __restrict__ wlist)
{
    const int t = blockIdx.x;
    const int lane = threadIdx.x;
    const bool vis = (tt[t] != 0);
    const float* rw   = vis ? rw_v : rw_t;
    const float* bias = vis ? b_v  : b_t;
    const float* xr = x + (size_t)t * HID;

    float acc[NEXP];
#pragma unroll
    for (int e = 0; e < NEXP; ++e) acc[e] = 0.f;
    for (int j = 0; j < HID; j += 64) {
        const float xv = xr[j + lane];
#pragma unroll
        for (int e = 0; e < NEXP; ++e)
            acc[e] = fmaf(xv, rw[(size_t)e * HID + j + lane], acc[e]);
    }
#pragma unroll
    for (int e = 0; e < NEXP; ++e) {
        float v = acc[e];
#pragma unroll
        for (int off = 32; off; off >>= 1) v += __shfl_xor(v, off);
        acc[e] = v;
    }
    if (lane < NEXP) out_logits[(size_t)t * NEXP + lane] = acc[lane];

    if (lane == 0) {
        float mx = acc[0];
#pragma unroll
        for (int e = 1; e < NEXP; ++e) mx = fmaxf(mx, acc[e]);
        float p[NEXP], s = 0.f;
#pragma unroll
        for (int e = 0; e < NEXP; ++e) { p[e] = expf(acc[e] - mx); s += p[e]; }
        const float inv = 1.f / s;
#pragma unroll
        for (int e = 0; e < NEXP; ++e) p[e] *= inv;

        int s1 = 0; float v1 = p[0] + bias[0];
#pragma unroll
        for (int e = 1; e < NEXP; ++e) {
            float c = p[e] + bias[e];
            if (c > v1) { v1 = c; s1 = e; }
        }
        int s2 = -1; float v2 = -1e30f;
#pragma unroll
        for (int e = 0; e < NEXP; ++e) {
            if (e == s1) continue;
            float c = p[e] + bias[e];
            if (c > v2) { v2 = c; s2 = e; }
        }
        float w1 = p[s1], w2 = p[s2];
        float sw = fmaxf(w1 + w2, 1e-12f);
        w1 /= sw; w2 /= sw;

        const int base = vis ? NEXP : 0;
        int pos1 = atomicAdd(&counts[base + s1], 1);
        lists[(base + s1) * TOK + pos1] = t * 2 + 0;
        wlist[(base + s1) * TOK + pos1] = w1;
        int pos2 = atomicAdd(&counts[base + s2], 1);
        lists[(base + s2) * TOK + pos2] = t * 2 + 1;
        wlist[(base + s2) * TOK + pos2] = w2;
    }
}

// ---------------- gate/up GEMM (routed z<32, shared z==32), bf16 MFMA ------
// wave tile 32m x 64n, block 4 waves = 64m x 128n. No LDS tiles, no K-loop
// barriers: fragments built directly from global fp32.
__global__ __launch_bounds__(256)
void k_gu(const float* __restrict__ X,
          const float* __restrict__ gut, const float* __restrict__ guv,
          const float* __restrict__ sg, const float* __restrict__ su,
          const int* __restrict__ counts, const int* __restrict__ lists,
          unsigned short* __restrict__ gu_buf, unsigned short* __restrict__ sgu)
{
    const int z = blockIdx.z;
    const bool sh = (z == 32);
    int M, N;
    const float* B = nullptr;
    if (sh) { M = 1024; N = 2048; }
    else {
        M = counts[z];
        const int mod = z >> 4, e = z & 15;
        N = mod ? 512 : 1024;
        B = mod ? (guv + (size_t)e * 1024 * 512) : (gut + (size_t)e * 1024 * 1024);
    }
    const int m0 = blockIdx.y * 64, n0 = blockIdx.x * 128;
    if (m0 >= M || n0 >= N) return;
    int bn0 = n0, bstr = N;
    if (sh) { B = (n0 < 1024) ? sg : su; bn0 = n0 & 1023; bstr = 1024; }

    __shared__ int s_aid[64];
    const int tid = threadIdx.x;
    if (tid < 64) {
        int r = m0 + tid;
        s_aid[tid] = sh ? r : ((r < M) ? lists[z * TOK + r] : -1);
    }
    __syncthreads();

    const int wid = tid >> 6, lane = tid & 63;
    const int lm = lane & 15, q = lane >> 4;
    const int wm = (wid >> 1) * 32, wn = (wid & 1) * 64;

    const float* arow[2];
#pragma unroll
    for (int s = 0; s < 2; ++s) {
        int aid = s_aid[wm + s * 16 + lm];
        int tr = sh ? aid : (aid < 0 ? 0 : (aid >> 1));
        arow[s] = X + (size_t)tr * HID;
    }
    const float* bcol[4];
#pragma unroll
    for (int t = 0; t < 4; ++t)
        bcol[t] = B + (size_t)(bn0 + wn + t * 16 + lm);

    f32x4 acc[2][4] = {};
    for (int k0 = 0; k0 < HID; k0 += 32) {
        const int kb = k0 + 8 * q;
        bf16x8 af[2], bfr[4];
#pragma unroll
        for (int s = 0; s < 2; ++s) {
            float4 lo = *(const float4*)(arow[s] + kb);
            float4 hi = *(const float4*)(arow[s] + kb + 4);
            union { bf16x8 v; unsigned d[4]; } u;
            u.d[0] = pack2(lo.x, lo.y); u.d[1] = pack2(lo.z, lo.w);
            u.d[2] = pack2(hi.x, hi.y); u.d[3] = pack2(hi.z, hi.w);
            af[s] = u.v;
        }
#pragma unroll
        for (int t = 0; t < 4; ++t) {
            const float* bp = bcol[t] + (size_t)kb * bstr;
            float b0 = bp[0], b1 = bp[(size_t)bstr], b2 = bp[(size_t)2 * bstr], b3 = bp[(size_t)3 * bstr];
            float b4 = bp[(size_t)4 * bstr], b5 = bp[(size_t)5 * bstr], b6 = bp[(size_t)6 * bstr], b7 = bp[(size_t)7 * bstr];
            union { bf16x8 v; unsigned d[4]; } u;
            u.d[0] = pack2(b0, b1); u.d[1] = pack2(b2, b3);
            u.d[2] = pack2(b4, b5); u.d[3] = pack2(b6, b7);
            bfr[t] = u.v;
        }
#pragma unroll
        for (int s = 0; s < 2; ++s)
#pragma unroll
            for (int t = 0; t < 4; ++t)
                acc[s][t] = __builtin_amdgcn_mfma_f32_16x16x32_bf16(af[s], bfr[t], acc[s][t], 0, 0, 0);
    }
#pragma unroll
    for (int s = 0; s < 2; ++s)
#pragma unroll
        for (int r = 0; r < 4; ++r) {
            int rl = wm + s * 16 + q * 4 + r;
            int aid = s_aid[rl];
            if (aid < 0) continue;
#pragma unroll
            for (int t = 0; t < 4; ++t) {
                int col = n0 + wn + t * 16 + lm;
                unsigned short v = (unsigned short)f2bf(acc[s][t][r]);
                if (sh) sgu[(size_t)aid * 2048 + col] = v;
                else    gu_buf[(size_t)aid * 1024 + col] = v;
            }
        }
}

// ---------------- down GEMM (routed z<32, shared z==32), bf16 MFMA ---------
// A = silu(g)*u computed in-register from bf16 gu rows; atomicAdd into out.
__global__ __launch_bounds__(256)
void k_down(const unsigned short* __restrict__ gu_buf, const unsigned short* __restrict__ sgu,
            const float* __restrict__ dnt, const float* __restrict__ dnv,
            const float* __restrict__ sd,
            const int* __restrict__ counts, const int* __restrict__ lists,
            const float* __restrict__ wlist,
            float* __restrict__ out)
{
    const int z = blockIdx.z;
    const bool sh = (z == 32);
    int M, K;
    const float* B;
    if (sh) { M = 1024; K = 1024; B = sd; }
    else {
        M = counts[z];
        const int mod = z >> 4, e = z & 15;
        K = mod ? 256 : 512;
        B = mod ? (dnv + (size_t)e * 256 * 1024) : (dnt + (size_t)e * 512 * 1024);
    }
    const int m0 = blockIdx.y * 64, n0 = blockIdx.x * 128;
    if (m0 >= M) return;

    __shared__ int s_aid[64];
    __shared__ float s_w[64];
    const int tid = threadIdx.x;
    if (tid < 64) {
        int r = m0 + tid;
        if (sh)          { s_aid[tid] = r; s_w[tid] = 1.f; }
        else if (r < M)  { s_aid[tid] = lists[z * TOK + r]; s_w[tid] = wlist[z * TOK + r]; }
        else             { s_aid[tid] = -1; s_w[tid] = 0.f; }
    }
    __syncthreads();

    const int wid = tid >> 6, lane = tid & 63;
    const int lm = lane & 15, q = lane >> 4;
    const int wm = (wid >> 1) * 32, wn = (wid & 1) * 64;

    const unsigned short* abase[2];
#pragma unroll
    for (int s = 0; s < 2; ++s) {
        int aid = s_aid[wm + s * 16 + lm];
        if (sh) abase[s] = sgu + (size_t)aid * 2048;
        else    abase[s] = gu_buf + (size_t)(aid < 0 ? 0 : aid) * 1024;
    }
    const float* bcol[4];
#pragma unroll
    for (int t = 0; t < 4; ++t)
        bcol[t] = B + (size_t)(n0 + wn + t * 16 + lm);

    f32x4 acc[2][4] = {};
    for (int k0 = 0; k0 < K; k0 += 32) {
        const int kb = k0 + 8 * q;
        bf16x8 af[2], bfr[4];
#pragma unroll
        for (int s = 0; s < 2; ++s) {
            u16x8 g8 = *(const u16x8*)(abase[s] + kb);
            u16x8 u8 = *(const u16x8*)(abase[s] + K + kb);
            float h[8];
#pragma unroll
            for (int j = 0; j < 8; ++j) {
                float g = bf2f((unsigned short)g8[j]);
                float uu = bf2f((unsigned short)u8[j]);
                h[j] = g / (1.f + __expf(-g)) * uu;
            }
            union { bf16x8 v; unsigned d[4]; } u;
            u.d[0] = pack2(h[0], h[1]); u.d[1] = pack2(h[2], h[3]);
            u.d[2] = pack2(h[4], h[5]); u.d[3] = pack2(h[6], h[7]);
            af[s] = u.v;
        }
#pragma unroll
        for (int t = 0; t < 4; ++t) {
            const float* bp = bcol[t] + (size_t)kb * HID;
            float b0 = bp[0], b1 = bp[(size_t)HID], b2 = bp[(size_t)2 * HID], b3 = bp[(size_t)3 * HID];
            float b4 = bp[(size_t)4 * HID], b5 = bp[(size_t)5 * HID], b6 = bp[(size_t)6 * HID], b7 = bp[(size_t)7 * HID];
            union { bf16x8 v; unsigned d[4]; } u;
            u.d[0] = pack2(b0, b1); u.d[1] = pack2(b2, b3);
            u.d[2] = pack2(b4, b5); u.d[3] = pack2(b6, b7);
            bfr[t] = u.v;
        }
#pragma unroll
        for (int s = 0; s < 2; ++s)
#pragma unroll
            for (int t = 0; t < 4; ++t)
                acc[s][t] = __builtin_amdgcn_mfma_f32_16x16x32_bf16(af[s], bfr[t], acc[s][t], 0, 0, 0);
    }
#pragma unroll
    for (int s = 0; s < 2; ++s)
#pragma unroll
        for (int r = 0; r < 4; ++r) {
            int rl = wm + s * 16 + q * 4 + r;
            int aid = s_aid[rl];
            if (aid < 0) continue;
            int tok = sh ? aid : (aid >> 1);
            float w = s_w[rl];
#pragma unroll
            for (int t = 0; t < 4; ++t) {
                int col = n0 + wn + t * 16 + lm;
                atomicAdd(&out[(size_t)tok * HID + col], w * acc[s][t][r]);
            }
        }
}

extern "C" void kernel_launch(void* const* d_in, const int* in_sizes, int n_in,
                              void* d_out, int out_size, void* d_ws, size_t ws_size,
                              hipStream_t stream)
{
    const float* x    = (const float*)d_in[0];
    const int*   tt   = (const int*)d_in[1];
    const float* rw_t = (const float*)d_in[2];
    const float* b_t  = (const float*)d_in[3];
    const float* gu_t = (const float*)d_in[4];
    const float* dn_t = (const float*)d_in[5];
    const float* rw_v = (const float*)d_in[6];
    const float* b_v  = (const float*)d_in[7];
    const float* gu_v = (const float*)d_in[8];
    const float* dn_v = (const float*)d_in[9];
    const float* sg   = (const float*)d_in[10];
    const float* su   = (const float*)d_in[11];
    const float* sd   = (const float*)d_in[12];
    float* out = (float*)d_out;
    float* out_logits = out + (size_t)TOK * HID;

    char* ws = (char*)d_ws;
    int*   counts = (int*)ws;                                   // 32 ints
    int*   lists  = (int*)(ws + 1024);                          // 32*1024 ints
    float* wlist  = (float*)(ws + 1024 + 32 * TOK * 4);         // 32*1024 floats
    unsigned short* gu_buf = (unsigned short*)(ws + 1024 + 64 * TOK * 4);      // 2048x1024 bf16 = 4 MB
    unsigned short* sgu    = gu_buf + (size_t)2048 * 1024;                     // 1024x2048 bf16 = 4 MB

    hipLaunchKernelGGL(k_init, dim3(1024), dim3(256), 0, stream, out, counts);
    hipLaunchKernelGGL(k_router, dim3(TOK), dim3(64), 0, stream,
                       x, tt, rw_t, b_t, rw_v, b_v, out_logits, counts, lists, wlist);
    hipLaunchKernelGGL(k_gu, dim3(16, 16, 33), dim3(256), 0, stream,
                       x, gu_t, gu_v, sg, su, counts, lists, gu_buf, sgu);
    hipLaunchKernelGGL(k_down, dim3(8, 16, 33), dim3(256), 0, stream,
                       gu_buf, sgu, dn_t, dn_v, sd, counts, lists, wlist, out);
}

// Round 3
// 441.823 us; speedup vs baseline: 1.4300x; 1.0197x over previous
//
#include <hip/hip_runtime.h>
#include <math.h>

#define TOK  1024
#define HID  1024
#define NEXP 16

typedef __attribute__((ext_vector_type(8))) short bf16x8;
typedef __attribute__((ext_vector_type(4))) float f32x4;

__device__ __forceinline__ unsigned pack2(float f0, float f1) {
    union { float f; unsigned u; } a, b; a.f = f0; b.f = f1;
    return __builtin_amdgcn_perm(b.u + 0x8000u, a.u + 0x8000u, 0x07060302u);
}
__device__ __forceinline__ unsigned short f2bf(float f) {
    union { float f; unsigned u; } v; v.f = f;
    return (unsigned short)((v.u + 0x8000u) >> 16);
}
// async global->LDS 16B per lane; lp must be wave-uniform (lane*16 implicit)
__device__ __forceinline__ void dma16(const float* gp, float* lp) {
    __builtin_amdgcn_global_load_lds(
        (const __attribute__((address_space(1))) unsigned int*)gp,
        (__attribute__((address_space(3))) unsigned int*)lp, 16, 0, 0);
}

// ---------------- init: zero counts + zero final-out region ----------------
__global__ void k_init(float* __restrict__ out, int* __restrict__ counts) {
    size_t i = (size_t)blockIdx.x * blockDim.x + threadIdx.x;   // 262144 float4
    ((float4*)out)[i] = make_float4(0.f, 0.f, 0.f, 0.f);
    if (blockIdx.x == 0 && threadIdx.x < 32) counts[threadIdx.x] = 0;
}

// ---------------- router: 1 wave per token (fp32 exact) --------------------
__global__ __launch_bounds__(64)
void k_router(const float* __restrict__ x, const int* __restrict__ tt,
              const float* __restrict__ rw_t, const float* __restrict__ b_t,
              const float* __restrict__ rw_v, const float* __restrict__ b_v,
              float* __restrict__ out_logits,
              int* __restrict__ counts, int* __restrict__ lists,
              float* __restrict__ wlist)
{
    const int t = blockIdx.x;
    const int lane = threadIdx.x;
    const bool vis = (tt[t] != 0);
    const float* rw   = vis ? rw_v : rw_t;
    const float* bias = vis ? b_v  : b_t;
    const float* xr = x + (size_t)t * HID;

    float acc[NEXP];
#pragma unroll
    for (int e = 0; e < NEXP; ++e) acc[e] = 0.f;
    for (int j = 0; j < HID; j += 64) {
        const float xv = xr[j + lane];
#pragma unroll
        for (int e = 0; e < NEXP; ++e)
            acc[e] = fmaf(xv, rw[(size_t)e * HID + j + lane], acc[e]);
    }
#pragma unroll
    for (int e = 0; e < NEXP; ++e) {
        float v = acc[e];
#pragma unroll
        for (int off = 32; off; off >>= 1) v += __shfl_xor(v, off);
        acc[e] = v;
    }
    if (lane < NEXP) out_logits[(size_t)t * NEXP + lane] = acc[lane];

    if (lane == 0) {
        float mx = acc[0];
#pragma unroll
        for (int e = 1; e < NEXP; ++e) mx = fmaxf(mx, acc[e]);
        float p[NEXP], s = 0.f;
#pragma unroll
        for (int e = 0; e < NEXP; ++e) { p[e] = expf(acc[e] - mx); s += p[e]; }
        const float inv = 1.f / s;
#pragma unroll
        for (int e = 0; e < NEXP; ++e) p[e] *= inv;

        int s1 = 0; float v1 = p[0] + bias[0];
#pragma unroll
        for (int e = 1; e < NEXP; ++e) {
            float c = p[e] + bias[e];
            if (c > v1) { v1 = c; s1 = e; }
        }
        int s2 = -1; float v2 = -1e30f;
#pragma unroll
        for (int e = 0; e < NEXP; ++e) {
            if (e == s1) continue;
            float c = p[e] + bias[e];
            if (c > v2) { v2 = c; s2 = e; }
        }
        float w1 = p[s1], w2 = p[s2];
        float sw = fmaxf(w1 + w2, 1e-12f);
        w1 /= sw; w2 /= sw;

        const int base = vis ? NEXP : 0;
        int pos1 = atomicAdd(&counts[base + s1], 1);
        lists[(base + s1) * TOK + pos1] = t * 2 + 0;
        wlist[(base + s1) * TOK + pos1] = w1;
        int pos2 = atomicAdd(&counts[base + s2], 1);
        lists[(base + s2) * TOK + pos2] = t * 2 + 1;
        wlist[(base + s2) * TOK + pos2] = w2;
    }
}

// ---------------- gate+up fused GEMM + silu  (routed z<32, shared z==32) ---
// Block: 64 m x 64 i-cols (gate cols 0-63 of chunk, up cols 64-127).
// B staged via global_load_lds DMA, double-buffered 64k x 128c fp32 chunks,
// XOR-swizzled cells so fragment ds_read_b32 is 2-way (free).
__global__ __launch_bounds__(256, 2)
void k_gu(const float* __restrict__ X,
          const float* __restrict__ gut, const float* __restrict__ guv,
          const float* __restrict__ sg, const float* __restrict__ su,
          const int* __restrict__ counts, const int* __restrict__ lists,
          unsigned short* __restrict__ hbuf, unsigned short* __restrict__ hsh)
{
    const int z = blockIdx.z;
    int M, I, str;
    const float *Wg, *Wu;
    if (z == 32) { M = TOK; I = 1024; str = 1024; Wg = sg; Wu = su; }
    else {
        M = counts[z];
        const int mod = z >> 4, e = z & 15;
        I = mod ? 256 : 512; str = 2 * I;
        const float* base = mod ? (guv + (size_t)e * HID * 512)
                                : (gut + (size_t)e * HID * 1024);
        Wg = base; Wu = base + I;
    }
    const int xI = blockIdx.x * 64;
    const int m0 = blockIdx.y * 64;
    if (xI >= I || m0 >= M) return;

    __shared__ float bs[2][8192];      // 2 x 32 KB chunks
    __shared__ int s_aid[64];

    const int tid = threadIdx.x;
    const int wid = tid >> 6, lane = tid & 63;
    const int lm = lane & 15, q = lane >> 4;

    if (tid < 64) {
        int r = m0 + tid;
        s_aid[tid] = (z == 32) ? r : ((r < M) ? lists[z * TOK + r] : -1);
    }
    __syncthreads();

    const float* arow[4];
#pragma unroll
    for (int s = 0; s < 4; ++s) {
        int aid = s_aid[s * 16 + lm];
        int tr = (z == 32) ? aid : (aid < 0 ? 0 : (aid >> 1));
        arow[s] = X + (size_t)tr * HID;
    }

    // per-thread DMA cell -> (k row, col4) with bank swizzle
    int urow[8], uc4[8];
#pragma unroll
    for (int r = 0; r < 8; ++r) {
        int u = r * 256 + tid;
        int k = u >> 5;
        urow[r] = k;
        uc4[r] = (u & 31) ^ (((k >> 3) & 1) << 2);
    }
    // fragment LDS float-index base (chunk-relative, at k = q*8)
    int fidx[2];
#pragma unroll
    for (int reg = 0; reg < 2; ++reg) {
        int c = reg * 64 + wid * 16 + lm;
        int cell = (q * 8) * 32 + ((c >> 2) ^ ((q & 1) << 2));
        fidx[reg] = cell * 4 + (c & 3);
    }

    // stage chunk 0
#pragma unroll
    for (int r = 0; r < 8; ++r) {
        int c4 = uc4[r];
        const float* gp = (c4 < 16) ? (Wg + (size_t)urow[r] * str + xI + c4 * 4)
                                    : (Wu + (size_t)urow[r] * str + xI + (c4 - 16) * 4);
        dma16(gp, &bs[0][r * 1024 + wid * 256]);
    }

    f32x4 accG[4] = {}, accU[4] = {};

    for (int kc = 0; kc < 16; ++kc) {
        __syncthreads();                       // chunk kc resident; prev reads done
        if (kc + 1 < 16) {
            const int k0 = (kc + 1) * 64;
            float* dst = bs[(kc + 1) & 1];
#pragma unroll
            for (int r = 0; r < 8; ++r) {
                int c4 = uc4[r];
                const float* gp = (c4 < 16) ? (Wg + (size_t)(k0 + urow[r]) * str + xI + c4 * 4)
                                            : (Wu + (size_t)(k0 + urow[r]) * str + xI + (c4 - 16) * 4);
                dma16(gp, dst + r * 1024 + wid * 256);
            }
        }
        const float* buf = bs[kc & 1];
#pragma unroll
        for (int ks = 0; ks < 64; ks += 32) {
            bf16x8 bg, bu;
            {
                float b[8];
#pragma unroll
                for (int j = 0; j < 8; ++j) b[j] = buf[fidx[0] + (ks + j) * 128];
                union { bf16x8 v; unsigned d[4]; } u;
                u.d[0] = pack2(b[0], b[1]); u.d[1] = pack2(b[2], b[3]);
                u.d[2] = pack2(b[4], b[5]); u.d[3] = pack2(b[6], b[7]);
                bg = u.v;
            }
            {
                float b[8];
#pragma unroll
                for (int j = 0; j < 8; ++j) b[j] = buf[fidx[1] + (ks + j) * 128];
                union { bf16x8 v; unsigned d[4]; } u;
                u.d[0] = pack2(b[0], b[1]); u.d[1] = pack2(b[2], b[3]);
                u.d[2] = pack2(b[4], b[5]); u.d[3] = pack2(b[6], b[7]);
                bu = u.v;
            }
            const int kg = kc * 64 + ks + q * 8;
#pragma unroll
            for (int s = 0; s < 4; ++s) {
                float4 lo = *(const float4*)(arow[s] + kg);
                float4 hi = *(const float4*)(arow[s] + kg + 4);
                union { bf16x8 v; unsigned d[4]; } u;
                u.d[0] = pack2(lo.x, lo.y); u.d[1] = pack2(lo.z, lo.w);
                u.d[2] = pack2(hi.x, hi.y); u.d[3] = pack2(hi.z, hi.w);
                accG[s] = __builtin_amdgcn_mfma_f32_16x16x32_bf16(u.v, bg, accG[s], 0, 0, 0);
                accU[s] = __builtin_amdgcn_mfma_f32_16x16x32_bf16(u.v, bu, accU[s], 0, 0, 0);
            }
        }
    }

    const int i = xI + wid * 16 + lm;
#pragma unroll
    for (int s = 0; s < 4; ++s)
#pragma unroll
        for (int r = 0; r < 4; ++r) {
            int row = s * 16 + q * 4 + r;
            int aid = s_aid[row];
            if (aid < 0) continue;
            float g = accG[s][r], uu = accU[s][r];
            float h = g / (1.f + __expf(-g)) * uu;
            if (z == 32) hsh[(size_t)aid * 1024 + i] = f2bf(h);
            else         hbuf[(size_t)aid * 512 + i] = f2bf(h);
        }
}

// ---------------- down GEMM (routed z<32, shared z==32) --------------------
// A = h (bf16, k-contiguous, direct global). B staged via DMA like k_gu.
__global__ __launch_bounds__(256, 2)
void k_down(const unsigned short* __restrict__ hbuf, const unsigned short* __restrict__ hsh,
            const float* __restrict__ dnt, const float* __restrict__ dnv,
            const float* __restrict__ sd,
            const int* __restrict__ counts, const int* __restrict__ lists,
            const float* __restrict__ wlist, float* __restrict__ out)
{
    const int z = blockIdx.z;
    int M, K;
    const float* W;
    if (z == 32) { M = TOK; K = 1024; W = sd; }
    else {
        M = counts[z];
        const int mod = z >> 4, e = z & 15;
        K = mod ? 256 : 512;
        W = mod ? (dnv + (size_t)e * 256 * 1024) : (dnt + (size_t)e * 512 * 1024);
    }
    const int n0 = blockIdx.x * 128;
    const int m0 = blockIdx.y * 64;
    if (m0 >= M) return;

    __shared__ float bs[2][8192];
    __shared__ int s_aid[64];
    __shared__ float s_w[64];

    const int tid = threadIdx.x;
    const int wid = tid >> 6, lane = tid & 63;
    const int lm = lane & 15, q = lane >> 4;

    if (tid < 64) {
        int r = m0 + tid;
        if (z == 32)    { s_aid[tid] = r; s_w[tid] = 1.f; }
        else if (r < M) { s_aid[tid] = lists[z * TOK + r]; s_w[tid] = wlist[z * TOK + r]; }
        else            { s_aid[tid] = -1; s_w[tid] = 0.f; }
    }
    __syncthreads();

    const unsigned short* hrow[4];
#pragma unroll
    for (int s = 0; s < 4; ++s) {
        int aid = s_aid[s * 16 + lm];
        hrow[s] = (z == 32) ? (hsh + (size_t)aid * 1024)
                            : (hbuf + (size_t)(aid < 0 ? 0 : aid) * 512);
    }

    int urow[8], uc4[8];
#pragma unroll
    for (int r = 0; r < 8; ++r) {
        int u = r * 256 + tid;
        int k = u >> 5;
        urow[r] = k;
        uc4[r] = (u & 31) ^ (((k >> 3) & 1) << 2);
    }
    int fidx[2];
#pragma unroll
    for (int t = 0; t < 2; ++t) {
        int c = wid * 32 + t * 16 + lm;
        int cell = (q * 8) * 32 + ((c >> 2) ^ ((q & 1) << 2));
        fidx[t] = cell * 4 + (c & 3);
    }

#pragma unroll
    for (int r = 0; r < 8; ++r)
        dma16(W + (size_t)urow[r] * 1024 + n0 + uc4[r] * 4,
              &bs[0][r * 1024 + wid * 256]);

    f32x4 acc[4][2] = {};
    const int NC = K >> 6;

    for (int kc = 0; kc < NC; ++kc) {
        __syncthreads();
        if (kc + 1 < NC) {
            const int k0 = (kc + 1) * 64;
            float* dst = bs[(kc + 1) & 1];
#pragma unroll
            for (int r = 0; r < 8; ++r)
                dma16(W + (size_t)(k0 + urow[r]) * 1024 + n0 + uc4[r] * 4,
                      dst + r * 1024 + wid * 256);
        }
        const float* buf = bs[kc & 1];
#pragma unroll
        for (int ks = 0; ks < 64; ks += 32) {
            bf16x8 bt[2];
#pragma unroll
            for (int t = 0; t < 2; ++t) {
                float b[8];
#pragma unroll
                for (int j = 0; j < 8; ++j) b[j] = buf[fidx[t] + (ks + j) * 128];
                union { bf16x8 v; unsigned d[4]; } u;
                u.d[0] = pack2(b[0], b[1]); u.d[1] = pack2(b[2], b[3]);
                u.d[2] = pack2(b[4], b[5]); u.d[3] = pack2(b[6], b[7]);
                bt[t] = u.v;
            }
            const int kg = kc * 64 + ks + q * 8;
#pragma unroll
            for (int s = 0; s < 4; ++s) {
                bf16x8 af = *(const bf16x8*)(hrow[s] + kg);
#pragma unroll
                for (int t = 0; t < 2; ++t)
                    acc[s][t] = __builtin_amdgcn_mfma_f32_16x16x32_bf16(af, bt[t], acc[s][t], 0, 0, 0);
            }
        }
    }

#pragma unroll
    for (int s = 0; s < 4; ++s)
#pragma unroll
        for (int r = 0; r < 4; ++r) {
            int row = s * 16 + q * 4 + r;
            int aid = s_aid[row];
            if (aid < 0) continue;
            int tok = (z == 32) ? aid : (aid >> 1);
            float w = s_w[row];
#pragma unroll
            for (int t = 0; t < 2; ++t) {
                int col = n0 + wid * 32 + t * 16 + lm;
                atomicAdd(&out[(size_t)tok * HID + col], w * acc[s][t][r]);
            }
        }
}

extern "C" void kernel_launch(void* const* d_in, const int* in_sizes, int n_in,
                              void* d_out, int out_size, void* d_ws, size_t ws_size,
                              hipStream_t stream)
{
    const float* x    = (const float*)d_in[0];
    const int*   tt   = (const int*)d_in[1];
    const float* rw_t = (const float*)d_in[2];
    const float* b_t  = (const float*)d_in[3];
    const float* gu_t = (const float*)d_in[4];
    const float* dn_t = (const float*)d_in[5];
    const float* rw_v = (const float*)d_in[6];
    const float* b_v  = (const float*)d_in[7];
    const float* gu_v = (const float*)d_in[8];
    const float* dn_v = (const float*)d_in[9];
    const float* sg   = (const float*)d_in[10];
    const float* su   = (const float*)d_in[11];
    const float* sd   = (const float*)d_in[12];
    float* out = (float*)d_out;
    float* out_logits = out + (size_t)TOK * HID;

    char* ws = (char*)d_ws;
    int*   counts = (int*)ws;                                   // 32 ints
    int*   lists  = (int*)(ws + 1024);                          // 32*1024 ints
    float* wlist  = (float*)(ws + 1024 + 32 * TOK * 4);         // 32*1024 floats
    unsigned short* hbuf = (unsigned short*)(ws + 1024 + 64 * TOK * 4);  // 2048x512 bf16 = 2 MB
    unsigned short* hsh  = hbuf + (size_t)2048 * 512;                    // 1024x1024 bf16 = 2 MB

    hipLaunchKernelGGL(k_init, dim3(1024), dim3(256), 0, stream, out, counts);
    hipLaunchKernelGGL(k_router, dim3(TOK), dim3(64), 0, stream,
                       x, tt, rw_t, b_t, rw_v, b_v, out_logits, counts, lists, wlist);
    hipLaunchKernelGGL(k_gu, dim3(16, 16, 33), dim3(256), 0, stream,
                       x, gu_t, gu_v, sg, su, counts, lists, hbuf, hsh);
    hipLaunchKernelGGL(k_down, dim3(8, 16, 33), dim3(256), 0, stream,
                       hbuf, hsh, dn_t, dn_v, sd, counts, lists, wlist, out);
}